// Round 5
// baseline (3191.375 us; speedup 1.0000x reference)
//
#include <hip/hip_runtime.h>
#include <stdint.h>

// TinyGRU producer-consumer: ONE launch, 256 blocks. Blocks 0..127 = layer0
// (producer), blocks 128..255 = layer1 (consumer) running concurrently ~32
// steps behind, fed through a 128-step ring in d_ws (16MB -> lives in L2/L3).
// Sync: per-pair progress flags, agent-scope release/acquire every 16 steps;
// ring data via nontemporal loads/stores (coherent at MALL, safe across ring
// wraps + XCDs). MFMA structure as R4 (CPB=4, 16x16x32 f16, weights in reg
// B-fragments). LDS h layout: [4 chains][140], A-fragments read chain col>>2
// (4-lane broadcast, <=2-way banks) -- unused D rows are garbage, never read.

typedef _Float16 half_t;
typedef _Float16 half8 __attribute__((ext_vector_type(8)));
typedef float f32x4 __attribute__((ext_vector_type(4)));

#define SS 1024
#define CPB 4
#define NPAIR 128        // producer/consumer block pairs
#define CT 4             // x register-queue depth (steps)
#define RS 128           // ring steps (power of 2)
#define CS 16            // sync chunk (steps)
#define HC 140           // LDS row stride, 128-wide h (f16 elems)
#define XC 68            // LDS row stride, 64-wide x (f16 elems)
#define RING_BYTES (512u * RS * 128u * 2u)   // 16.78 MB

#define MFMA16(a, b, c) __builtin_amdgcn_mfma_f32_16x16x32_f16(a, b, c, 0, 0, 0)

__device__ __forceinline__ float sigmoidf_(float x) {
    return __builtin_amdgcn_rcpf(1.0f + __expf(-x));
}
__device__ __forceinline__ float tanhf_(float x) {
    return 1.0f - 2.0f * __builtin_amdgcn_rcpf(1.0f + __expf(2.0f * x));
}
__device__ __forceinline__ half8 cvt8(const float* p) {
    f32x4 a = *(const f32x4*)p;
    f32x4 b = *(const f32x4*)(p + 4);
    half8 r;
    r[0] = (half_t)a[0]; r[1] = (half_t)a[1]; r[2] = (half_t)a[2]; r[3] = (half_t)a[3];
    r[4] = (half_t)b[0]; r[5] = (half_t)b[1]; r[6] = (half_t)b[2]; r[7] = (half_t)b[3];
    return r;
}
__device__ __forceinline__ int ld_acq(const int* p) {
    return __hip_atomic_load(p, __ATOMIC_ACQUIRE, __HIP_MEMORY_SCOPE_AGENT);
}
__device__ __forceinline__ void st_rel(int* p, int v) {
    __hip_atomic_store(p, v, __ATOMIC_RELEASE, __HIP_MEMORY_SCOPE_AGENT);
}

__global__ __launch_bounds__(512, 2)
void gru_pc(const float* __restrict__ x,
            const float* __restrict__ Wih0, const float* __restrict__ Whh0,
            const float* __restrict__ bih0, const float* __restrict__ bhh0,
            const float* __restrict__ Wih1, const float* __restrict__ Whh1,
            const float* __restrict__ bih1, const float* __restrict__ bhh1,
            const float* __restrict__ fcw, const float* __restrict__ fcb,
            uint32_t* __restrict__ ring, int* __restrict__ flags,
            float* __restrict__ out)
{
    const int tid  = threadIdx.x;
    const int w    = tid >> 6;
    const int lane = tid & 63;
    const int quad = lane >> 4;
    const int col  = lane & 15;
    const int role = blockIdx.x >> 7;        // 0 = layer0, 1 = layer1
    const int pb   = blockIdx.x & (NPAIR - 1);
    const int cb   = pb * CPB;
    int* pflag = flags + pb;                 // producer progress
    int* cflag = flags + NPAIR + pb;         // consumer progress

    __shared__ alignas(16) half_t s_x[2][CT][4 * XC];   // producer x chunks
    __shared__ alignas(16) half_t s_h[2][4 * HC];       // producer h
    __shared__ alignas(16) half_t c_x[2][4 * HC];       // consumer x (=h0)
    __shared__ alignas(16) half_t c_h[2][4 * HC];       // consumer h

    const int rr   = w * 16 + col;           // gate row (within gate) / h unit
    const int c    = (tid >> 6) & 3;         // staging: chain
    const int sc   = tid & 63;               // staging: col
    const int arow = (col >> 2);             // A-fragment chain (broadcast x4)
    uint32_t* ringp = ring + (size_t)(cb + c) * RS * 64 + sc;

    if (role == 0) {
        // ==================== PRODUCER: layer 0 ====================
        half8 Bxr[2], Bxz[2], Bxn[2], Bhr[4], Bhz[4], Bhn[4];
#pragma unroll
        for (int s = 0; s < 2; ++s) {
            Bxr[s] = cvt8(Wih0 + (rr      ) * 64 + s * 32 + quad * 8);
            Bxz[s] = cvt8(Wih0 + (rr + 128) * 64 + s * 32 + quad * 8);
            Bxn[s] = cvt8(Wih0 + (rr + 256) * 64 + s * 32 + quad * 8);
        }
#pragma unroll
        for (int s = 0; s < 4; ++s) {
            Bhr[s] = cvt8(Whh0 + (rr      ) * 128 + s * 32 + quad * 8);
            Bhz[s] = cvt8(Whh0 + (rr + 128) * 128 + s * 32 + quad * 8);
            Bhn[s] = cvt8(Whh0 + (rr + 256) * 128 + s * 32 + quad * 8);
        }
        const float br  = bih0[rr] + bhh0[rr];
        const float bz  = bih0[128 + rr] + bhh0[128 + rr];
        const float bni = bih0[256 + rr];
        const float bnh = bhh0[256 + rr];

        for (int i = tid; i < 4 * HC; i += 512) s_h[0][i] = (half_t)0.0f;

        const float* xrow = x + (size_t)(cb + c) * SS * 64 + sc;
        float gq[CT];
        if (tid < 256) {
#pragma unroll
            for (int i = 0; i < CT; ++i) gq[i] = xrow[i * 64];
#pragma unroll
            for (int i = 0; i < CT; ++i)
                s_x[0][i][c * XC + sc] = (half_t)gq[i];
#pragma unroll
            for (int i = 0; i < CT; ++i) gq[i] = xrow[(CT + i) * 64];
        }
        __syncthreads();

        float hp = 0.0f;

        for (int t = 0; t < SS; ++t) {
            const int cur = t & 1, nxt = cur ^ 1;

            // back-pressure: don't overwrite ring slots consumer still needs
            if ((t & (CS - 1)) == 0 && t >= RS) {
                if (tid == 0)
                    while (ld_acq(cflag) < t - (RS - CS)) __builtin_amdgcn_s_sleep(8);
                __syncthreads();
            }
            // ring store h[t-1] (stable in s_h[cur]); 2 units per thread
            if (t >= 1 && tid < 256) {
                uint32_t v = *(const uint32_t*)&s_h[cur][c * HC + 2 * sc];
                __builtin_nontemporal_store(v, ringp + (size_t)((t - 1) & (RS - 1)) * 64);
            }

            f32x4 ar  = {br, br, br, br},     az  = {bz, bz, bz, bz};
            f32x4 ani = {bni, bni, bni, bni}, anh = {bnh, bnh, bnh, bnh};
#pragma unroll
            for (int s = 0; s < 2; ++s) {
                half8 ax = *(const half8*)&s_x[(t >> 2) & 1][t & 3]
                                              [arow * XC + s * 32 + quad * 8];
                ar  = MFMA16(ax, Bxr[s], ar);
                az  = MFMA16(ax, Bxz[s], az);
                ani = MFMA16(ax, Bxn[s], ani);
            }
#pragma unroll
            for (int s = 0; s < 4; ++s) {
                half8 ah = *(const half8*)&s_h[cur][arow * HC + s * 32 + quad * 8];
                ar  = MFMA16(ah, Bhr[s], ar);
                az  = MFMA16(ah, Bhz[s], az);
                anh = MFMA16(ah, Bhn[s], anh);
            }
            {   // chain = quad (D row 4*quad, reg 0)
                float r = sigmoidf_(ar[0]);
                float z = sigmoidf_(az[0]);
                float n = tanhf_(ani[0] + r * anh[0]);
                hp = n + z * (hp - n);
                s_h[nxt][quad * HC + rr] = (half_t)hp;
            }
            // signal progress (before refill issues new loads)
            if ((t & (CS - 1)) == (CS - 1)) {
                __threadfence();
                __syncthreads();
                if (tid == 0) st_rel(pflag, t);
            }
            // x chunk refill every 4 steps
            if ((t & 3) == 3 && t + 1 < SS && tid < 256) {
                const int c1 = (t + 1) >> 2;
#pragma unroll
                for (int i = 0; i < CT; ++i)
                    s_x[c1 & 1][i][c * XC + sc] = (half_t)gq[i];
                const int base = (c1 + 1) * CT;
                if (base < SS) {
#pragma unroll
                    for (int i = 0; i < CT; ++i)
                        gq[i] = xrow[(size_t)(base + i) * 64];
                }
            }
            __syncthreads();
        }
        // tail: h[1023] sits in s_h[0]
        if (tid < 256) {
            uint32_t v = *(const uint32_t*)&s_h[0][c * HC + 2 * sc];
            __builtin_nontemporal_store(v, ringp + (size_t)((SS - 1) & (RS - 1)) * 64);
        }
        __threadfence();
        __syncthreads();
        if (tid == 0) st_rel(pflag, SS);
    } else {
        // ==================== CONSUMER: layer 1 ====================
        half8 Bxr[4], Bxz[4], Bxn[4], Bhr[4], Bhz[4], Bhn[4];
#pragma unroll
        for (int s = 0; s < 4; ++s) {
            Bxr[s] = cvt8(Wih1 + (rr      ) * 128 + s * 32 + quad * 8);
            Bxz[s] = cvt8(Wih1 + (rr + 128) * 128 + s * 32 + quad * 8);
            Bxn[s] = cvt8(Wih1 + (rr + 256) * 128 + s * 32 + quad * 8);
            Bhr[s] = cvt8(Whh1 + (rr      ) * 128 + s * 32 + quad * 8);
            Bhz[s] = cvt8(Whh1 + (rr + 128) * 128 + s * 32 + quad * 8);
            Bhn[s] = cvt8(Whh1 + (rr + 256) * 128 + s * 32 + quad * 8);
        }
        const float br  = bih1[rr] + bhh1[rr];
        const float bz  = bih1[128 + rr] + bhh1[128 + rr];
        const float bni = bih1[256 + rr];
        const float bnh = bhh1[256 + rr];

        for (int i = tid; i < 4 * HC; i += 512) c_h[0][i] = (half_t)0.0f;

        // wait for first chunk, then stage x_0 = h0[0]
        if (tid == 0)
            while (ld_acq(pflag) < CS + 1) __builtin_amdgcn_s_sleep(8);
        __syncthreads();
        if (tid < 256) {
            uint32_t v = __builtin_nontemporal_load(ringp);
            *(uint32_t*)&c_x[0][c * HC + 2 * sc] = v;
        }
        __syncthreads();

        float hp = 0.0f;

        for (int t = 0; t < SS; ++t) {
            const int cur = t & 1, nxt = cur ^ 1;

            if ((t & (CS - 1)) == 0 && t) {
                if (tid == 0) {
                    int target = t + CS + 1; if (target > SS) target = SS;
                    while (ld_acq(pflag) < target) __builtin_amdgcn_s_sleep(8);
                }
                __syncthreads();
            }
            uint32_t g = 0u;
            const bool pf = (tid < 256) && (t + 1 < SS);
            if (pf) g = __builtin_nontemporal_load(
                            ringp + (size_t)((t + 1) & (RS - 1)) * 64);

            f32x4 ar  = {br, br, br, br},     az  = {bz, bz, bz, bz};
            f32x4 ani = {bni, bni, bni, bni}, anh = {bnh, bnh, bnh, bnh};
#pragma unroll
            for (int s = 0; s < 4; ++s) {
                half8 ax = *(const half8*)&c_x[cur][arow * HC + s * 32 + quad * 8];
                half8 ah = *(const half8*)&c_h[cur][arow * HC + s * 32 + quad * 8];
                ar  = MFMA16(ax, Bxr[s], ar);
                ar  = MFMA16(ah, Bhr[s], ar);
                az  = MFMA16(ax, Bxz[s], az);
                az  = MFMA16(ah, Bhz[s], az);
                ani = MFMA16(ax, Bxn[s], ani);
                anh = MFMA16(ah, Bhn[s], anh);
            }
            {
                float r = sigmoidf_(ar[0]);
                float z = sigmoidf_(az[0]);
                float n = tanhf_(ani[0] + r * anh[0]);
                hp = n + z * (hp - n);
                c_h[nxt][quad * HC + rr] = (half_t)hp;
            }
            if (pf) *(uint32_t*)&c_x[nxt][c * HC + 2 * sc] = g;
            if ((t & (CS - 1)) == (CS - 1) && tid == 0) st_rel(cflag, t);
            __syncthreads();
        }

        // FC epilogue: h_final (t=1023, nxt=0) rows 0..3 of c_h[0]
        if (tid < 40) {
            const int ch = tid / 10, cl = tid - ch * 10;
            float acc = fcb[cl];
            const float* wr = fcw + cl * 128;
            const half_t* hv = &c_h[0][ch * HC];
#pragma unroll 8
            for (int k = 0; k < 128; ++k) acc += (float)hv[k] * wr[k];
            out[(cb + ch) * 10 + cl] = acc;
        }
    }
}

extern "C" void kernel_launch(void* const* d_in, const int* in_sizes, int n_in,
                              void* d_out, int out_size, void* d_ws, size_t ws_size,
                              hipStream_t stream) {
    const float* x    = (const float*)d_in[0];
    const float* Wih0 = (const float*)d_in[1];
    const float* Whh0 = (const float*)d_in[2];
    const float* bih0 = (const float*)d_in[3];
    const float* bhh0 = (const float*)d_in[4];
    const float* Wih1 = (const float*)d_in[5];
    const float* Whh1 = (const float*)d_in[6];
    const float* bih1 = (const float*)d_in[7];
    const float* bhh1 = (const float*)d_in[8];
    const float* fcw  = (const float*)d_in[9];
    const float* fcb  = (const float*)d_in[10];

    uint32_t* ring = (uint32_t*)d_ws;                       // 16.78 MB
    int* flags = (int*)((char*)d_ws + RING_BYTES);          // 2*128 ints

    hipMemsetAsync(flags, 0, 2 * NPAIR * sizeof(int), stream);
    gru_pc<<<2 * NPAIR, 512, 0, stream>>>(x, Wih0, Whh0, bih0, bhh0,
                                          Wih1, Whh1, bih1, bhh1,
                                          fcw, fcb, ring, flags,
                                          (float*)d_out);
}